// Round 9
// baseline (426.972 us; speedup 1.0000x reference)
//
#include <hip/hip_runtime.h>
#include <cstdint>
#include <cstddef>

typedef unsigned short ushort_t;
typedef unsigned int uint_t;
typedef __attribute__((ext_vector_type(8))) short bf16x8;
typedef __attribute__((ext_vector_type(4))) float f32x4;

#define NBMAX 1024   // max buckets (N <= 131072)
#define EPB   16384  // edges per block in hist/scatter passes
#define LDK   136    // padded k-stride (bf16 units) for LDS W^T

__device__ inline ushort_t f2bf(float f) {
  uint_t u = __float_as_uint(f);
  uint_t r = (u + 0x7fffu + ((u >> 16) & 1u)) >> 16;
  return (ushort_t)r;
}
__device__ inline float bfl(uint_t u) { return __uint_as_float(u << 16); }
__device__ inline float bfh(uint_t u) { return __uint_as_float(u & 0xffff0000u); }
__device__ inline float bf1(ushort_t v) { return __uint_as_float(((uint_t)v) << 16); }

// ---------------- CSR construction: bucketed counting sort ----------------

__global__ void bucket_hist_kernel(const int* __restrict__ edst, int* __restrict__ gcount,
                                   int* __restrict__ myBase, int E, int NB) {
  __shared__ int hist[NBMAX];
  int t = threadIdx.x;
  int blk = blockIdx.x;
  for (int i = t; i < NB; i += 256) hist[i] = 0;
  __syncthreads();
  int b0 = blk * EPB, e1 = min(b0 + EPB, E);
  for (int i = b0 + t; i < e1; i += 256) atomicAdd(&hist[edst[i] >> 7], 1);
  __syncthreads();
  for (int i = t; i < NB; i += 256) {
    int c = hist[i];
    myBase[(size_t)blk * NB + i] = c ? atomicAdd(&gcount[i], c) : 0;
  }
}

__global__ void bucket_scan_kernel(const int* __restrict__ gcount, int* __restrict__ boff, int NB) {
  __shared__ int ws[16];
  int t = threadIdx.x;
  int lane = t & 63, w = t >> 6;
  int v = (t < NB) ? gcount[t] : 0;
  for (int o = 1; o < 64; o <<= 1) { int y = __shfl_up(v, o); if (lane >= o) v += y; }
  if (lane == 63) ws[w] = v;
  __syncthreads();
  if (t < 16) {
    int s = ws[t];
    for (int o = 1; o < 16; o <<= 1) { int y = __shfl_up(s, o); if (t >= o) s += y; }
    ws[t] = s;
  }
  __syncthreads();
  if (w > 0) v += ws[w - 1];
  if (t < NB) boff[t + 1] = v;
  if (t == 0) boff[0] = 0;
}

// packed pair: (dst & 127) << 25 | src   (requires src < 2^25)
__global__ void bucket_scatter_kernel(const int* __restrict__ esrc, const int* __restrict__ edst,
                                      const int* __restrict__ boff, const int* __restrict__ myBase,
                                      uint_t* __restrict__ pairs, int E, int NB) {
  __shared__ int cursor[NBMAX];
  int t = threadIdx.x;
  int blk = blockIdx.x;
  for (int i = t; i < NB; i += 256) cursor[i] = boff[i] + myBase[(size_t)blk * NB + i];
  __syncthreads();
  int b0 = blk * EPB, e1 = min(b0 + EPB, E);
  for (int i = b0 + t; i < e1; i += 256) {
    int d = edst[i], s = esrc[i];
    int pos = atomicAdd(&cursor[d >> 7], 1);
    pairs[pos] = ((uint_t)(d & 127) << 25) | (uint_t)s;
  }
}

__global__ void bucket_csr_kernel(const uint_t* __restrict__ pairs, const int* __restrict__ boff,
                                  int* __restrict__ rowptr, int* __restrict__ csr, int n, int NB) {
  __shared__ int cnt[128];
  __shared__ int ws2[2];
  int b = blockIdx.x;
  int t = threadIdx.x;   // 128 threads
  int lo = boff[b], hi = boff[b + 1];
  int D0 = b << 7;
  cnt[t] = 0;
  __syncthreads();
  for (int i = lo + t; i < hi; i += 128) atomicAdd(&cnt[pairs[i] >> 25], 1);
  __syncthreads();
  int lane = t & 63, w = t >> 6;
  int v = cnt[t];
  int vx = v;
  for (int o = 1; o < 64; o <<= 1) { int y = __shfl_up(vx, o); if (lane >= o) vx += y; }
  if (lane == 63) ws2[w] = vx;
  __syncthreads();
  int incl = vx + (w ? ws2[0] : 0);
  int excl = incl - v;
  int d = D0 + t;
  if (d <= n) rowptr[d] = lo + excl;
  __syncthreads();
  cnt[t] = excl;
  __syncthreads();
  for (int i = lo + t; i < hi; i += 128) {
    uint_t pr = pairs[i];
    int pos = atomicAdd(&cnt[pr >> 25], 1);
    csr[lo + pos] = (int)(pr & 0x1FFFFFFu);
  }
}

// ---------------- GEMM1 + att1 fused (MFMA): h1b(bf16) = x@W1; a_s/a_d (f32) ----------------
__global__ void gemm1_att1_kernel(const float* __restrict__ x, const float* __restrict__ W,
                                  const float* __restrict__ asw, const float* __restrict__ adw,
                                  ushort_t* __restrict__ h1b, float* __restrict__ a_s,
                                  float* __restrict__ a_d, int n) {
  __shared__ ushort_t wT[128 * LDK];
  int t = threadIdx.x;
  {
    int nn = t & 127;
    int kp0 = t >> 7;                    // 0..1
    for (int kp = kp0; kp < 64; kp += 2) {
      float w0 = W[(size_t)(2 * kp) * 128 + nn];
      float w1 = W[(size_t)(2 * kp + 1) * 128 + nn];
      *(uint_t*)&wT[nn * LDK + 2 * kp] = (uint_t)f2bf(w0) | ((uint_t)f2bf(w1) << 16);
    }
  }
  __syncthreads();

  int lane = t & 63, w = t >> 6;
  int g = lane >> 4, cl = lane & 15;
  int rowA = blockIdx.x * 64 + w * 16 + cl;       // A-operand row for this lane
  const float* xr = x + (size_t)(rowA < n ? rowA : 0) * 128;

  bf16x8 afr[4];
  #pragma unroll
  for (int c = 0; c < 4; ++c) {
    float4 v0 = *(const float4*)(xr + c * 32 + g * 8);
    float4 v1 = *(const float4*)(xr + c * 32 + g * 8 + 4);
    bf16x8 a;
    a[0] = (short)f2bf(v0.x); a[1] = (short)f2bf(v0.y);
    a[2] = (short)f2bf(v0.z); a[3] = (short)f2bf(v0.w);
    a[4] = (short)f2bf(v1.x); a[5] = (short)f2bf(v1.y);
    a[6] = (short)f2bf(v1.z); a[7] = (short)f2bf(v1.w);
    afr[c] = a;
  }

  int orow0 = blockIdx.x * 64 + w * 16 + g * 4;   // D rows base for this lane
  #pragma unroll 2
  for (int tt = 0; tt < 8; ++tt) {
    f32x4 acc = {0.f, 0.f, 0.f, 0.f};
    #pragma unroll
    for (int c = 0; c < 4; ++c) {
      bf16x8 bfr = *(const bf16x8*)&wT[(tt * 16 + cl) * LDK + c * 32 + g * 8];
      acc = __builtin_amdgcn_mfma_f32_16x16x32_bf16(afr[c], bfr, acc, 0, 0, 0);
    }
    float asv = asw[tt * 16 + cl], adv = adw[tt * 16 + cl];
    float ps[4], pd[4];
    ushort_t hb[4];
    #pragma unroll
    for (int r = 0; r < 4; ++r) {
      float v = acc[r];
      hb[r] = f2bf(v);
      ps[r] = v * asv; pd[r] = v * adv;
    }
    #pragma unroll
    for (int o = 1; o < 16; o <<= 1) {
      #pragma unroll
      for (int r = 0; r < 4; ++r) { ps[r] += __shfl_xor(ps[r], o); pd[r] += __shfl_xor(pd[r], o); }
    }
    #pragma unroll
    for (int r = 0; r < 4; ++r) {
      int rr = orow0 + r;
      if (rr < n) {
        h1b[(size_t)rr * 128 + tt * 16 + cl] = hb[r];
        if (cl == 0) {
          a_s[(size_t)rr * 8 + tt] = ps[r];
          a_d[(size_t)rr * 8 + tt] = pd[r];
        }
      }
    }
  }
}

// ---------------- alpha1: normalized attention weights, layer 1 ----------------
__global__ void alpha1_kernel(const int* __restrict__ rowptr, const int* __restrict__ csr_src,
                              const float* __restrict__ a_s, const float* __restrict__ a_d,
                              ushort_t* __restrict__ alpha1, int n) {
  int t = threadIdx.x & 63;
  int w = threadIdx.x >> 6;
  int dst = blockIdx.x * 4 + w;
  if (dst >= n) return;
  int beg = rowptr[dst], end = rowptr[dst + 1];
  if (beg == end) return;
  int h = t & 7, el = t >> 3;
  float adv = a_d[(size_t)dst * 8 + h];
  float M = -1e30f, S = 0.f;
  for (int base = beg; base < end; base += 8) {
    int eidx = base + el;
    bool valid = eidx < end;
    int s = csr_src[valid ? eidx : beg];
    float e = a_s[(size_t)s * 8 + h] + adv;
    e = e > 0.f ? e : 0.2f * e;
    e = valid ? e : -1e30f;
    float m = e;
    m = fmaxf(m, __shfl_xor(m, 8));
    m = fmaxf(m, __shfl_xor(m, 16));
    m = fmaxf(m, __shfl_xor(m, 32));
    float nm = fmaxf(M, m);
    float p = valid ? __expf(e - nm) : 0.f;
    float ps = p;
    ps += __shfl_xor(ps, 8);
    ps += __shfl_xor(ps, 16);
    ps += __shfl_xor(ps, 32);
    S = S * __expf(M - nm) + ps;
    M = nm;
  }
  float inv = 1.f / (S + 1e-16f);
  for (int base = beg; base < end; base += 8) {
    int eidx = base + el;
    if (eidx < end) {
      int s = csr_src[eidx];
      float e = a_s[(size_t)s * 8 + h] + adv;
      e = e > 0.f ? e : 0.2f * e;
      alpha1[(size_t)eidx * 8 + h] = f2bf(__expf(e - M) * inv);
    }
  }
}

// ---------------- GAT layer 1 aggregate: 8 edges/wave, 8 lanes/edge ----------------
// lane = (slot = lane>>3, c8 = lane&7); lane owns channels c8*16..c8*16+15 (= head c8).
__global__ void gat1_agg_kernel(const int* __restrict__ rowptr, const int* __restrict__ csr_src,
                                const ushort_t* __restrict__ h1b,
                                const ushort_t* __restrict__ alpha1,
                                const float* __restrict__ b1, ushort_t* __restrict__ hmidb, int n) {
  int lane = threadIdx.x & 63;
  int w = threadIdx.x >> 6;
  int dst = blockIdx.x * 4 + w;
  if (dst >= n) return;
  int beg = rowptr[dst], end = rowptr[dst + 1];
  int slot = lane >> 3, c8 = lane & 7;
  float acc[16] = {};
  #pragma unroll 2
  for (int e = beg + slot; e < end; e += 8) {
    int si = csr_src[e];
    float a = bf1(alpha1[(size_t)e * 8 + c8]);
    const ushort_t* hp = h1b + (size_t)si * 128 + c8 * 16;
    uint4 hv0 = *(const uint4*)hp;
    uint4 hv1 = *(const uint4*)(hp + 8);
    acc[0]  = fmaf(a, bfl(hv0.x), acc[0]);
    acc[1]  = fmaf(a, bfh(hv0.x), acc[1]);
    acc[2]  = fmaf(a, bfl(hv0.y), acc[2]);
    acc[3]  = fmaf(a, bfh(hv0.y), acc[3]);
    acc[4]  = fmaf(a, bfl(hv0.z), acc[4]);
    acc[5]  = fmaf(a, bfh(hv0.z), acc[5]);
    acc[6]  = fmaf(a, bfl(hv0.w), acc[6]);
    acc[7]  = fmaf(a, bfh(hv0.w), acc[7]);
    acc[8]  = fmaf(a, bfl(hv1.x), acc[8]);
    acc[9]  = fmaf(a, bfh(hv1.x), acc[9]);
    acc[10] = fmaf(a, bfl(hv1.y), acc[10]);
    acc[11] = fmaf(a, bfh(hv1.y), acc[11]);
    acc[12] = fmaf(a, bfl(hv1.z), acc[12]);
    acc[13] = fmaf(a, bfh(hv1.z), acc[13]);
    acc[14] = fmaf(a, bfl(hv1.w), acc[14]);
    acc[15] = fmaf(a, bfh(hv1.w), acc[15]);
  }
  #pragma unroll
  for (int i = 0; i < 16; ++i) {
    acc[i] += __shfl_xor(acc[i], 8);
    acc[i] += __shfl_xor(acc[i], 16);
    acc[i] += __shfl_xor(acc[i], 32);
  }
  if (slot == 0) {
    float4 bb0 = *(const float4*)&b1[c8 * 16];
    float4 bb1 = *(const float4*)&b1[c8 * 16 + 4];
    float4 bb2 = *(const float4*)&b1[c8 * 16 + 8];
    float4 bb3 = *(const float4*)&b1[c8 * 16 + 12];
    float bv[16] = { bb0.x, bb0.y, bb0.z, bb0.w, bb1.x, bb1.y, bb1.z, bb1.w,
                     bb2.x, bb2.y, bb2.z, bb2.w, bb3.x, bb3.y, bb3.z, bb3.w };
    ushort_t ob[16];
    #pragma unroll
    for (int i = 0; i < 16; ++i) {
      float v = acc[i] + bv[i];
      v = v > 0.f ? v : (__expf(v) - 1.f);
      ob[i] = f2bf(v);
    }
    *(uint4*)(hmidb + (size_t)dst * 128 + c8 * 16) = *(uint4*)ob;
    *(uint4*)(hmidb + (size_t)dst * 128 + c8 * 16 + 8) = *(uint4*)(ob + 8);
  }
}

// ---------------- GEMM2 + att2 fused (MFMA): h2b = hmid(bf16) @ W2; a_s2/a_d2 ----------------
__global__ void gemm2_att2_kernel(const ushort_t* __restrict__ hmidb, const float* __restrict__ W2,
                                  const float* __restrict__ asw, const float* __restrict__ adw,
                                  ushort_t* __restrict__ h2b, float* __restrict__ a_s2,
                                  float* __restrict__ a_d2, int n) {
  __shared__ ushort_t wT[16 * LDK];
  int t = threadIdx.x;
  if (t < 128) {
    int nn = t & 15, kp0 = t >> 4;     // 0..7
    for (int kp = kp0; kp < 64; kp += 8) {
      float w0 = W2[(size_t)(2 * kp) * 16 + nn];
      float w1 = W2[(size_t)(2 * kp + 1) * 16 + nn];
      *(uint_t*)&wT[nn * LDK + 2 * kp] = (uint_t)f2bf(w0) | ((uint_t)f2bf(w1) << 16);
    }
  }
  __syncthreads();

  int lane = t & 63, w = t >> 6;
  int g = lane >> 4, cl = lane & 15;
  int rowA = blockIdx.x * 64 + w * 16 + cl;
  const ushort_t* hr = hmidb + (size_t)(rowA < n ? rowA : 0) * 128;

  f32x4 acc = {0.f, 0.f, 0.f, 0.f};
  #pragma unroll
  for (int c = 0; c < 4; ++c) {
    bf16x8 afr = *(const bf16x8*)(hr + c * 32 + g * 8);
    bf16x8 bfr = *(const bf16x8*)&wT[cl * LDK + c * 32 + g * 8];
    acc = __builtin_amdgcn_mfma_f32_16x16x32_bf16(afr, bfr, acc, 0, 0, 0);
  }
  float asv = asw[cl], adv = adw[cl];
  float ps[4], pd[4];
  ushort_t hb[4];
  #pragma unroll
  for (int r = 0; r < 4; ++r) {
    float v = acc[r];
    hb[r] = f2bf(v);
    ps[r] = v * asv; pd[r] = v * adv;
  }
  #pragma unroll
  for (int o = 1; o < 16; o <<= 1) {
    #pragma unroll
    for (int r = 0; r < 4; ++r) { ps[r] += __shfl_xor(ps[r], o); pd[r] += __shfl_xor(pd[r], o); }
  }
  int orow0 = blockIdx.x * 64 + w * 16 + g * 4;
  #pragma unroll
  for (int r = 0; r < 4; ++r) {
    int rr = orow0 + r;
    if (rr < n) {
      h2b[(size_t)rr * 16 + cl] = hb[r];
      if (cl == 0) { a_s2[rr] = ps[r]; a_d2[rr] = pd[r]; }
    }
  }
}

// ---------------- alpha2: normalized attention weights, layer 2 (1 head) ----------------
__global__ void alpha2_kernel(const int* __restrict__ rowptr, const int* __restrict__ csr_src,
                              const float* __restrict__ a_s2, const float* __restrict__ a_d2,
                              float* __restrict__ alpha2, int n) {
  int t = threadIdx.x & 63;
  int w = threadIdx.x >> 6;
  int dst = blockIdx.x * 4 + w;
  if (dst >= n) return;
  int beg = rowptr[dst], end = rowptr[dst + 1];
  if (beg == end) return;
  float adv = a_d2[dst];
  float M = -1e30f, S = 0.f;
  for (int base = beg; base < end; base += 64) {
    int eidx = base + t;
    bool valid = eidx < end;
    int s = csr_src[valid ? eidx : beg];
    float e = a_s2[s] + adv;
    e = e > 0.f ? e : 0.2f * e;
    e = valid ? e : -1e30f;
    float m = e;
    #pragma unroll
    for (int o = 1; o < 64; o <<= 1) m = fmaxf(m, __shfl_xor(m, o));
    float nm = fmaxf(M, m);
    float p = valid ? __expf(e - nm) : 0.f;
    float ps = p;
    #pragma unroll
    for (int o = 1; o < 64; o <<= 1) ps += __shfl_xor(ps, o);
    S = S * __expf(M - nm) + ps;
    M = nm;
  }
  float inv = 1.f / (S + 1e-16f);
  for (int base = beg; base < end; base += 64) {
    int eidx = base + t;
    if (eidx < end) {
      int s = csr_src[eidx];
      float e = a_s2[s] + adv;
      e = e > 0.f ? e : 0.2f * e;
      alpha2[eidx] = __expf(e - M) * inv;
    }
  }
}

// ---------------- GAT layer 2 aggregate + pooled atomics (16-lane group per dst) ----------------
// LDS-staged (src,alpha) per group -> 16 independent gathers in flight, no shfl chain.
__global__ void gat2_agg_kernel(const int* __restrict__ rowptr, const int* __restrict__ csr_src,
                                const ushort_t* __restrict__ h2b,
                                const float* __restrict__ alpha2, const float* __restrict__ b2,
                                const int* __restrict__ batch,
                                float* __restrict__ pooled, float* __restrict__ cntb,
                                int n, int G) {
  __shared__ float pooledL[17][16];
  __shared__ float cntL[17];
  __shared__ int   s_lds[16][16];
  __shared__ float a_lds[16][16];
  int t = threadIdx.x;
  if (t < 17) cntL[t] = 0.f;
  for (int i = t; i < 17 * 16; i += 256) ((float*)pooledL)[i] = 0.f;
  __syncthreads();

  int grp = t >> 4, c = t & 15;
  int dst = blockIdx.x * 16 + grp;
  int gfirst = batch[blockIdx.x * 16];

  if (dst < n) {
    int beg = rowptr[dst], end = rowptr[dst + 1];
    float acc = 0.f;
    for (int base = beg; base < end; base += 16) {
      int idx = base + c;
      bool v = idx < end;
      s_lds[grp][c] = v ? csr_src[idx] : 0;
      a_lds[grp][c] = v ? alpha2[idx] : 0.f;
      // quarter-wave group: ds_write by all 16 lanes precedes ds_read in program
      // order within one wave -> no barrier needed.
      #pragma unroll
      for (int j = 0; j < 16; ++j) {
        acc = fmaf(a_lds[grp][j], bf1(h2b[(size_t)s_lds[grp][j] * 16 + c]), acc);
      }
    }
    float v = acc + b2[c];
    int g = batch[dst];
    int gi = g - gfirst;
    if (gi <= 16) {
      atomicAdd(&pooledL[gi][c], v);
      if (c == 0) atomicAdd(&cntL[gi], 1.f);
    } else {
      atomicAdd(&pooled[g * 16 + c], v);
      if (c == 0) atomicAdd(&cntb[g], 1.f);
    }
  }
  __syncthreads();

  int w = t >> 5, lane32 = t & 31;
  for (int gi = w; gi < 17; gi += 8) {
    if (cntL[gi] > 0.f) {
      int g = gfirst + gi;
      if (lane32 < 16) atomicAdd(&pooled[g * 16 + lane32], pooledL[gi][lane32]);
      else if (lane32 == 16) atomicAdd(&cntb[g], cntL[gi]);
    }
  }
}

// ---------------- final: mean + log_softmax ----------------
__global__ void final_kernel(const float* __restrict__ pooled, const float* __restrict__ cntb,
                             float* __restrict__ out, int G) {
  int g = threadIdx.x;
  if (g >= G) return;
  float c = fmaxf(cntb[g], 1.f);
  float v[16];
  float m = -1e30f;
  #pragma unroll
  for (int i = 0; i < 16; ++i) { v[i] = pooled[g * 16 + i] / c; m = fmaxf(m, v[i]); }
  float s = 0.f;
  #pragma unroll
  for (int i = 0; i < 16; ++i) s += __expf(v[i] - m);
  float ls = logf(s);
  #pragma unroll
  for (int i = 0; i < 16; ++i) out[g * 16 + i] = v[i] - m - ls;
}

// ---------------- launcher ----------------
extern "C" void kernel_launch(void* const* d_in, const int* in_sizes, int n_in,
                              void* d_out, int out_size, void* d_ws, size_t ws_size,
                              hipStream_t stream) {
  const float* x    = (const float*)d_in[0];
  const int*   eidx = (const int*)  d_in[1];
  const int*   batch= (const int*)  d_in[2];
  const float* W1   = (const float*)d_in[3];
  const float* as1w = (const float*)d_in[4];
  const float* ad1w = (const float*)d_in[5];
  const float* b1   = (const float*)d_in[6];
  const float* W2   = (const float*)d_in[7];
  const float* as2w = (const float*)d_in[8];
  const float* ad2w = (const float*)d_in[9];
  const float* b2   = (const float*)d_in[10];
  float* out = (float*)d_out;

  int N = in_sizes[0] / 128;
  int E = in_sizes[1] / 2;
  int G = out_size / 16;
  const int* esrc = eidx;
  const int* edst = eidx + E;

  int NB = (N + 127) >> 7;
  int nblkA = (E + EPB - 1) / EPB;

  char* p = (char*)d_ws;
  auto alloc = [&](size_t bytes) {
    char* r = p;
    p += (bytes + 255) & ~(size_t)255;
    return r;
  };
  ushort_t* h1b = (ushort_t*)alloc((size_t)N * 128 * 2);
  ushort_t* hmidb = (ushort_t*)alloc((size_t)N * 128 * 2);
  ushort_t* h2b = (ushort_t*)alloc((size_t)N * 16 * 2);
  float* as1  = (float*)alloc((size_t)N * 8 * 4);
  float* ad1  = (float*)alloc((size_t)N * 8 * 4);
  float* as2  = (float*)alloc((size_t)N * 4);
  float* ad2  = (float*)alloc((size_t)N * 4);
  // union: pairs (E*4 B) is dead before alpha1/alpha2 are produced
  size_t a1sz = (size_t)E * 8 * 2, a2sz = (size_t)E * 4;
  size_t unionSz = a1sz + a2sz;
  char* U = alloc(unionSz);
  uint_t* pairs = (uint_t*)U;
  ushort_t* alpha1 = (ushort_t*)U;
  float* alpha2 = (float*)(U + a1sz);
  float* pooled = (float*)alloc((size_t)(G * 16 + G) * 4);
  float* cntb = pooled + G * 16;
  int* rowptr = (int*)alloc((size_t)(N + 1) * 4);
  int* csr    = (int*)alloc((size_t)E * 4);
  int* gcount = (int*)alloc((size_t)(NBMAX + 1) * 4);
  int* boff   = (int*)alloc((size_t)(NBMAX + 1) * 4);
  int* myBase = (int*)alloc((size_t)nblkA * NB * 4);

  hipMemsetAsync(gcount, 0, (size_t)(NBMAX + 1) * 4, stream);
  hipMemsetAsync(pooled, 0, (size_t)(G * 16 + G) * 4, stream);

  bucket_hist_kernel<<<nblkA, 256, 0, stream>>>(edst, gcount, myBase, E, NB);
  bucket_scan_kernel<<<1, 1024, 0, stream>>>(gcount, boff, NB);
  bucket_scatter_kernel<<<nblkA, 256, 0, stream>>>(esrc, edst, boff, myBase, pairs, E, NB);
  bucket_csr_kernel<<<NB, 128, 0, stream>>>(pairs, boff, rowptr, csr, N, NB);

  gemm1_att1_kernel<<<(N + 63) / 64, 256, 0, stream>>>(x, W1, as1w, ad1w, h1b, as1, ad1, N);
  alpha1_kernel<<<(N + 3) / 4, 256, 0, stream>>>(rowptr, csr, as1, ad1, alpha1, N);
  gat1_agg_kernel<<<(N + 3) / 4, 256, 0, stream>>>(rowptr, csr, h1b, alpha1, b1, hmidb, N);
  gemm2_att2_kernel<<<(N + 63) / 64, 256, 0, stream>>>(hmidb, W2, as2w, ad2w, h2b, as2, ad2, N);
  alpha2_kernel<<<(N + 3) / 4, 256, 0, stream>>>(rowptr, csr, as2, ad2, alpha2, N);
  gat2_agg_kernel<<<(N + 15) / 16, 256, 0, stream>>>(rowptr, csr, h2b, alpha2, b2, batch, pooled, cntb, N, G);
  final_kernel<<<1, (G + 63) / 64 * 64, 0, stream>>>(pooled, cntb, out, G);
}

// Round 10
// 404.270 us; speedup vs baseline: 1.0562x; 1.0562x over previous
//
#include <hip/hip_runtime.h>
#include <cstdint>
#include <cstddef>

typedef unsigned short ushort_t;
typedef unsigned int uint_t;
typedef __attribute__((ext_vector_type(8))) short bf16x8;
typedef __attribute__((ext_vector_type(4))) float f32x4;

#define NBMAX 1024   // max buckets (N <= 131072)
#define EPB   16384  // edges per block in hist/scatter passes
#define LDK   136    // padded k-stride (bf16 units) for LDS W^T

__device__ inline ushort_t f2bf(float f) {
  uint_t u = __float_as_uint(f);
  uint_t r = (u + 0x7fffu + ((u >> 16) & 1u)) >> 16;
  return (ushort_t)r;
}
__device__ inline float bfl(uint_t u) { return __uint_as_float(u << 16); }
__device__ inline float bfh(uint_t u) { return __uint_as_float(u & 0xffff0000u); }
__device__ inline float bf1(ushort_t v) { return __uint_as_float(((uint_t)v) << 16); }

// ---------------- CSR construction: bucketed counting sort ----------------

__global__ void bucket_hist_kernel(const int* __restrict__ edst, int* __restrict__ gcount,
                                   int* __restrict__ myBase, int E, int NB) {
  __shared__ int hist[NBMAX];
  int t = threadIdx.x;
  int blk = blockIdx.x;
  for (int i = t; i < NB; i += 256) hist[i] = 0;
  __syncthreads();
  int b0 = blk * EPB, e1 = min(b0 + EPB, E);
  for (int i = b0 + t; i < e1; i += 256) atomicAdd(&hist[edst[i] >> 7], 1);
  __syncthreads();
  for (int i = t; i < NB; i += 256) {
    int c = hist[i];
    myBase[(size_t)blk * NB + i] = c ? atomicAdd(&gcount[i], c) : 0;
  }
}

__global__ void bucket_scan_kernel(const int* __restrict__ gcount, int* __restrict__ boff, int NB) {
  __shared__ int ws[16];
  int t = threadIdx.x;
  int lane = t & 63, w = t >> 6;
  int v = (t < NB) ? gcount[t] : 0;
  for (int o = 1; o < 64; o <<= 1) { int y = __shfl_up(v, o); if (lane >= o) v += y; }
  if (lane == 63) ws[w] = v;
  __syncthreads();
  if (t < 16) {
    int s = ws[t];
    for (int o = 1; o < 16; o <<= 1) { int y = __shfl_up(s, o); if (t >= o) s += y; }
    ws[t] = s;
  }
  __syncthreads();
  if (w > 0) v += ws[w - 1];
  if (t < NB) boff[t + 1] = v;
  if (t == 0) boff[0] = 0;
}

// packed pair: (dst & 127) << 25 | src   (requires src < 2^25)
__global__ void bucket_scatter_kernel(const int* __restrict__ esrc, const int* __restrict__ edst,
                                      const int* __restrict__ boff, const int* __restrict__ myBase,
                                      uint_t* __restrict__ pairs, int E, int NB) {
  __shared__ int cursor[NBMAX];
  int t = threadIdx.x;
  int blk = blockIdx.x;
  for (int i = t; i < NB; i += 256) cursor[i] = boff[i] + myBase[(size_t)blk * NB + i];
  __syncthreads();
  int b0 = blk * EPB, e1 = min(b0 + EPB, E);
  for (int i = b0 + t; i < e1; i += 256) {
    int d = edst[i], s = esrc[i];
    int pos = atomicAdd(&cursor[d >> 7], 1);
    pairs[pos] = ((uint_t)(d & 127) << 25) | (uint_t)s;
  }
}

__global__ void bucket_csr_kernel(const uint_t* __restrict__ pairs, const int* __restrict__ boff,
                                  int* __restrict__ rowptr, int* __restrict__ csr, int n, int NB) {
  __shared__ int cnt[128];
  __shared__ int ws2[2];
  int b = blockIdx.x;
  int t = threadIdx.x;   // 128 threads
  int lo = boff[b], hi = boff[b + 1];
  int D0 = b << 7;
  cnt[t] = 0;
  __syncthreads();
  for (int i = lo + t; i < hi; i += 128) atomicAdd(&cnt[pairs[i] >> 25], 1);
  __syncthreads();
  int lane = t & 63, w = t >> 6;
  int v = cnt[t];
  int vx = v;
  for (int o = 1; o < 64; o <<= 1) { int y = __shfl_up(vx, o); if (lane >= o) vx += y; }
  if (lane == 63) ws2[w] = vx;
  __syncthreads();
  int incl = vx + (w ? ws2[0] : 0);
  int excl = incl - v;
  int d = D0 + t;
  if (d <= n) rowptr[d] = lo + excl;
  __syncthreads();
  cnt[t] = excl;
  __syncthreads();
  for (int i = lo + t; i < hi; i += 128) {
    uint_t pr = pairs[i];
    int pos = atomicAdd(&cnt[pr >> 25], 1);
    csr[lo + pos] = (int)(pr & 0x1FFFFFFu);
  }
}

// ---------------- GEMM1 + att1 fused (MFMA): h1b(bf16) = x@W1; a_s/a_d (f32) ----------------
// 128 rows/block (2 row-tiles/wave) to amortize W1 LDS staging.
__global__ void gemm1_att1_kernel(const float* __restrict__ x, const float* __restrict__ W,
                                  const float* __restrict__ asw, const float* __restrict__ adw,
                                  ushort_t* __restrict__ h1b, float* __restrict__ a_s,
                                  float* __restrict__ a_d, int n) {
  __shared__ ushort_t wT[128 * LDK];
  int t = threadIdx.x;
  {
    int nn = t & 127;
    int kp0 = t >> 7;                    // 0..1
    for (int kp = kp0; kp < 64; kp += 2) {
      float w0 = W[(size_t)(2 * kp) * 128 + nn];
      float w1 = W[(size_t)(2 * kp + 1) * 128 + nn];
      *(uint_t*)&wT[nn * LDK + 2 * kp] = (uint_t)f2bf(w0) | ((uint_t)f2bf(w1) << 16);
    }
  }
  __syncthreads();

  int lane = t & 63, w = t >> 6;
  int g = lane >> 4, cl = lane & 15;

  #pragma unroll
  for (int rt = 0; rt < 2; ++rt) {
    int rowA = blockIdx.x * 128 + rt * 64 + w * 16 + cl;
    const float* xr = x + (size_t)(rowA < n ? rowA : 0) * 128;

    bf16x8 afr[4];
    #pragma unroll
    for (int c = 0; c < 4; ++c) {
      float4 v0 = *(const float4*)(xr + c * 32 + g * 8);
      float4 v1 = *(const float4*)(xr + c * 32 + g * 8 + 4);
      bf16x8 a;
      a[0] = (short)f2bf(v0.x); a[1] = (short)f2bf(v0.y);
      a[2] = (short)f2bf(v0.z); a[3] = (short)f2bf(v0.w);
      a[4] = (short)f2bf(v1.x); a[5] = (short)f2bf(v1.y);
      a[6] = (short)f2bf(v1.z); a[7] = (short)f2bf(v1.w);
      afr[c] = a;
    }

    int orow0 = blockIdx.x * 128 + rt * 64 + w * 16 + g * 4;
    #pragma unroll 2
    for (int tt = 0; tt < 8; ++tt) {
      f32x4 acc = {0.f, 0.f, 0.f, 0.f};
      #pragma unroll
      for (int c = 0; c < 4; ++c) {
        bf16x8 bfr = *(const bf16x8*)&wT[(tt * 16 + cl) * LDK + c * 32 + g * 8];
        acc = __builtin_amdgcn_mfma_f32_16x16x32_bf16(afr[c], bfr, acc, 0, 0, 0);
      }
      float asv = asw[tt * 16 + cl], adv = adw[tt * 16 + cl];
      float ps[4], pd[4];
      ushort_t hb[4];
      #pragma unroll
      for (int r = 0; r < 4; ++r) {
        float v = acc[r];
        hb[r] = f2bf(v);
        ps[r] = v * asv; pd[r] = v * adv;
      }
      #pragma unroll
      for (int o = 1; o < 16; o <<= 1) {
        #pragma unroll
        for (int r = 0; r < 4; ++r) { ps[r] += __shfl_xor(ps[r], o); pd[r] += __shfl_xor(pd[r], o); }
      }
      #pragma unroll
      for (int r = 0; r < 4; ++r) {
        int rr = orow0 + r;
        if (rr < n) {
          h1b[(size_t)rr * 128 + tt * 16 + cl] = hb[r];
          if (cl == 0) {
            a_s[(size_t)rr * 8 + tt] = ps[r];
            a_d[(size_t)rr * 8 + tt] = pd[r];
          }
        }
      }
    }
  }
}

// ---------------- alpha1: normalized attention weights, layer 1 ----------------
// fast path deg<=64: raw e cached in LDS (wave-private, no barrier) -> no 2nd gather.
__global__ void alpha1_kernel(const int* __restrict__ rowptr, const int* __restrict__ csr_src,
                              const float* __restrict__ a_s, const float* __restrict__ a_d,
                              ushort_t* __restrict__ alpha1, int n) {
  __shared__ float e_lds[4][64][8];
  int t = threadIdx.x & 63;
  int w = threadIdx.x >> 6;
  int dst = blockIdx.x * 4 + w;
  if (dst >= n) return;
  int beg = rowptr[dst], end = rowptr[dst + 1];
  int deg = end - beg;
  if (deg == 0) return;
  int h = t & 7, el = t >> 3;
  float adv = a_d[(size_t)dst * 8 + h];
  float M = -1e30f, S = 0.f;

  if (deg <= 64) {
    int nch = (deg + 7) >> 3;
    for (int it = 0; it < nch; ++it) {
      int eidx = beg + it * 8 + el;
      bool valid = eidx < end;
      int s = csr_src[valid ? eidx : beg];
      float eraw = a_s[(size_t)s * 8 + h] + adv;
      eraw = eraw > 0.f ? eraw : 0.2f * eraw;
      e_lds[w][it * 8 + el][h] = eraw;
      float e = valid ? eraw : -1e30f;
      float m = e;
      m = fmaxf(m, __shfl_xor(m, 8));
      m = fmaxf(m, __shfl_xor(m, 16));
      m = fmaxf(m, __shfl_xor(m, 32));
      float nm = fmaxf(M, m);
      float p = valid ? __expf(e - nm) : 0.f;
      float ps = p;
      ps += __shfl_xor(ps, 8);
      ps += __shfl_xor(ps, 16);
      ps += __shfl_xor(ps, 32);
      S = S * __expf(M - nm) + ps;
      M = nm;
    }
    float inv = 1.f / (S + 1e-16f);
    for (int it = 0; it < nch; ++it) {
      int eidx = beg + it * 8 + el;
      if (eidx < end) {
        float e = e_lds[w][it * 8 + el][h];
        alpha1[(size_t)eidx * 8 + h] = f2bf(__expf(e - M) * inv);
      }
    }
  } else {
    for (int base = beg; base < end; base += 8) {
      int eidx = base + el;
      bool valid = eidx < end;
      int s = csr_src[valid ? eidx : beg];
      float e = a_s[(size_t)s * 8 + h] + adv;
      e = e > 0.f ? e : 0.2f * e;
      e = valid ? e : -1e30f;
      float m = e;
      m = fmaxf(m, __shfl_xor(m, 8));
      m = fmaxf(m, __shfl_xor(m, 16));
      m = fmaxf(m, __shfl_xor(m, 32));
      float nm = fmaxf(M, m);
      float p = valid ? __expf(e - nm) : 0.f;
      float ps = p;
      ps += __shfl_xor(ps, 8);
      ps += __shfl_xor(ps, 16);
      ps += __shfl_xor(ps, 32);
      S = S * __expf(M - nm) + ps;
      M = nm;
    }
    float inv = 1.f / (S + 1e-16f);
    for (int base = beg; base < end; base += 8) {
      int eidx = base + el;
      if (eidx < end) {
        int s = csr_src[eidx];
        float e = a_s[(size_t)s * 8 + h] + adv;
        e = e > 0.f ? e : 0.2f * e;
        alpha1[(size_t)eidx * 8 + h] = f2bf(__expf(e - M) * inv);
      }
    }
  }
}

// ---------------- GAT layer 1 aggregate: 4 edges/wave, 16 lanes/edge ----------------
__global__ void gat1_agg_kernel(const int* __restrict__ rowptr, const int* __restrict__ csr_src,
                                const ushort_t* __restrict__ h1b,
                                const ushort_t* __restrict__ alpha1,
                                const float* __restrict__ b1, ushort_t* __restrict__ hmidb, int n) {
  int lane = threadIdx.x & 63;
  int w = threadIdx.x >> 6;
  int dst = blockIdx.x * 4 + w;
  if (dst >= n) return;
  int beg = rowptr[dst], end = rowptr[dst + 1];
  int slot = lane >> 4, c8 = lane & 15;
  int hh = c8 >> 1;
  float acc[8] = {};
  #pragma unroll 2
  for (int e = beg + slot; e < end; e += 4) {
    int si = csr_src[e];
    float a = bf1(alpha1[(size_t)e * 8 + hh]);
    uint4 hv = *(const uint4*)(h1b + (size_t)si * 128 + c8 * 8);
    acc[0] = fmaf(a, bfl(hv.x), acc[0]);
    acc[1] = fmaf(a, bfh(hv.x), acc[1]);
    acc[2] = fmaf(a, bfl(hv.y), acc[2]);
    acc[3] = fmaf(a, bfh(hv.y), acc[3]);
    acc[4] = fmaf(a, bfl(hv.z), acc[4]);
    acc[5] = fmaf(a, bfh(hv.z), acc[5]);
    acc[6] = fmaf(a, bfl(hv.w), acc[6]);
    acc[7] = fmaf(a, bfh(hv.w), acc[7]);
  }
  #pragma unroll
  for (int i = 0; i < 8; ++i) {
    acc[i] += __shfl_xor(acc[i], 16);
    acc[i] += __shfl_xor(acc[i], 32);
  }
  if (slot == 0) {
    ushort_t ob[8];
    #pragma unroll
    for (int i = 0; i < 8; ++i) {
      float v = acc[i] + b1[c8 * 8 + i];
      v = v > 0.f ? v : (__expf(v) - 1.f);
      ob[i] = f2bf(v);
    }
    *(uint4*)(hmidb + (size_t)dst * 128 + c8 * 8) = *(uint4*)ob;
  }
}

// ---------------- GEMM2 + att2 fused (MFMA): h2b = hmid(bf16) @ W2; a_s2/a_d2 ----------------
__global__ void gemm2_att2_kernel(const ushort_t* __restrict__ hmidb, const float* __restrict__ W2,
                                  const float* __restrict__ asw, const float* __restrict__ adw,
                                  ushort_t* __restrict__ h2b, float* __restrict__ a_s2,
                                  float* __restrict__ a_d2, int n) {
  __shared__ ushort_t wT[16 * LDK];
  int t = threadIdx.x;
  if (t < 128) {
    int nn = t & 15, kp0 = t >> 4;     // 0..7
    for (int kp = kp0; kp < 64; kp += 8) {
      float w0 = W2[(size_t)(2 * kp) * 16 + nn];
      float w1 = W2[(size_t)(2 * kp + 1) * 16 + nn];
      *(uint_t*)&wT[nn * LDK + 2 * kp] = (uint_t)f2bf(w0) | ((uint_t)f2bf(w1) << 16);
    }
  }
  __syncthreads();

  int lane = t & 63, w = t >> 6;
  int g = lane >> 4, cl = lane & 15;
  int rowA = blockIdx.x * 64 + w * 16 + cl;
  const ushort_t* hr = hmidb + (size_t)(rowA < n ? rowA : 0) * 128;

  f32x4 acc = {0.f, 0.f, 0.f, 0.f};
  #pragma unroll
  for (int c = 0; c < 4; ++c) {
    bf16x8 afr = *(const bf16x8*)(hr + c * 32 + g * 8);
    bf16x8 bfr = *(const bf16x8*)&wT[cl * LDK + c * 32 + g * 8];
    acc = __builtin_amdgcn_mfma_f32_16x16x32_bf16(afr, bfr, acc, 0, 0, 0);
  }
  float asv = asw[cl], adv = adw[cl];
  float ps[4], pd[4];
  ushort_t hb[4];
  #pragma unroll
  for (int r = 0; r < 4; ++r) {
    float v = acc[r];
    hb[r] = f2bf(v);
    ps[r] = v * asv; pd[r] = v * adv;
  }
  #pragma unroll
  for (int o = 1; o < 16; o <<= 1) {
    #pragma unroll
    for (int r = 0; r < 4; ++r) { ps[r] += __shfl_xor(ps[r], o); pd[r] += __shfl_xor(pd[r], o); }
  }
  int orow0 = blockIdx.x * 64 + w * 16 + g * 4;
  #pragma unroll
  for (int r = 0; r < 4; ++r) {
    int rr = orow0 + r;
    if (rr < n) {
      h2b[(size_t)rr * 16 + cl] = hb[r];
      if (cl == 0) { a_s2[rr] = ps[r]; a_d2[rr] = pd[r]; }
    }
  }
}

// ---------------- alpha2: normalized attention weights, layer 2 (1 head) ----------------
// fast path deg<=64: single chunk, e held in register.
__global__ void alpha2_kernel(const int* __restrict__ rowptr, const int* __restrict__ csr_src,
                              const float* __restrict__ a_s2, const float* __restrict__ a_d2,
                              float* __restrict__ alpha2, int n) {
  int t = threadIdx.x & 63;
  int w = threadIdx.x >> 6;
  int dst = blockIdx.x * 4 + w;
  if (dst >= n) return;
  int beg = rowptr[dst], end = rowptr[dst + 1];
  int deg = end - beg;
  if (deg == 0) return;
  float adv = a_d2[dst];

  if (deg <= 64) {
    int eidx = beg + t;
    bool valid = eidx < end;
    int s = csr_src[valid ? eidx : beg];
    float e = a_s2[s] + adv;
    e = e > 0.f ? e : 0.2f * e;
    float ev = valid ? e : -1e30f;
    float m = ev;
    #pragma unroll
    for (int o = 1; o < 64; o <<= 1) m = fmaxf(m, __shfl_xor(m, o));
    float p = valid ? __expf(ev - m) : 0.f;
    float S = p;
    #pragma unroll
    for (int o = 1; o < 64; o <<= 1) S += __shfl_xor(S, o);
    if (valid) alpha2[eidx] = p / (S + 1e-16f);
    return;
  }

  float M = -1e30f, S = 0.f;
  for (int base = beg; base < end; base += 64) {
    int eidx = base + t;
    bool valid = eidx < end;
    int s = csr_src[valid ? eidx : beg];
    float e = a_s2[s] + adv;
    e = e > 0.f ? e : 0.2f * e;
    e = valid ? e : -1e30f;
    float m = e;
    #pragma unroll
    for (int o = 1; o < 64; o <<= 1) m = fmaxf(m, __shfl_xor(m, o));
    float nm = fmaxf(M, m);
    float p = valid ? __expf(e - nm) : 0.f;
    float ps = p;
    #pragma unroll
    for (int o = 1; o < 64; o <<= 1) ps += __shfl_xor(ps, o);
    S = S * __expf(M - nm) + ps;
    M = nm;
  }
  float inv = 1.f / (S + 1e-16f);
  for (int base = beg; base < end; base += 64) {
    int eidx = base + t;
    if (eidx < end) {
      int s = csr_src[eidx];
      float e = a_s2[s] + adv;
      e = e > 0.f ? e : 0.2f * e;
      alpha2[eidx] = __expf(e - M) * inv;
    }
  }
}

// ---------------- GAT layer 2 aggregate + pooled atomics (16-lane group per dst) ----------------
__global__ void gat2_agg_kernel(const int* __restrict__ rowptr, const int* __restrict__ csr_src,
                                const ushort_t* __restrict__ h2b,
                                const float* __restrict__ alpha2, const float* __restrict__ b2,
                                const int* __restrict__ batch,
                                float* __restrict__ pooled, float* __restrict__ cntb,
                                int n, int G) {
  __shared__ float pooledL[17][16];
  __shared__ float cntL[17];
  __shared__ int   s_lds[16][16];
  __shared__ float a_lds[16][16];
  int t = threadIdx.x;
  if (t < 17) cntL[t] = 0.f;
  for (int i = t; i < 17 * 16; i += 256) ((float*)pooledL)[i] = 0.f;
  __syncthreads();

  int grp = t >> 4, c = t & 15;
  int dst = blockIdx.x * 16 + grp;
  int gfirst = batch[blockIdx.x * 16];

  if (dst < n) {
    int beg = rowptr[dst], end = rowptr[dst + 1];
    float acc = 0.f;
    for (int base = beg; base < end; base += 16) {
      int idx = base + c;
      bool v = idx < end;
      s_lds[grp][c] = v ? csr_src[idx] : 0;
      a_lds[grp][c] = v ? alpha2[idx] : 0.f;
      #pragma unroll
      for (int j = 0; j < 16; ++j) {
        acc = fmaf(a_lds[grp][j], bf1(h2b[(size_t)s_lds[grp][j] * 16 + c]), acc);
      }
    }
    float v = acc + b2[c];
    int g = batch[dst];
    int gi = g - gfirst;
    if (gi <= 16) {
      atomicAdd(&pooledL[gi][c], v);
      if (c == 0) atomicAdd(&cntL[gi], 1.f);
    } else {
      atomicAdd(&pooled[g * 16 + c], v);
      if (c == 0) atomicAdd(&cntb[g], 1.f);
    }
  }
  __syncthreads();

  int w = t >> 5, lane32 = t & 31;
  for (int gi = w; gi < 17; gi += 8) {
    if (cntL[gi] > 0.f) {
      int g = gfirst + gi;
      if (lane32 < 16) atomicAdd(&pooled[g * 16 + lane32], pooledL[gi][lane32]);
      else if (lane32 == 16) atomicAdd(&cntb[g], cntL[gi]);
    }
  }
}

// ---------------- final: mean + log_softmax ----------------
__global__ void final_kernel(const float* __restrict__ pooled, const float* __restrict__ cntb,
                             float* __restrict__ out, int G) {
  int g = threadIdx.x;
  if (g >= G) return;
  float c = fmaxf(cntb[g], 1.f);
  float v[16];
  float m = -1e30f;
  #pragma unroll
  for (int i = 0; i < 16; ++i) { v[i] = pooled[g * 16 + i] / c; m = fmaxf(m, v[i]); }
  float s = 0.f;
  #pragma unroll
  for (int i = 0; i < 16; ++i) s += __expf(v[i] - m);
  float ls = logf(s);
  #pragma unroll
  for (int i = 0; i < 16; ++i) out[g * 16 + i] = v[i] - m - ls;
}

// ---------------- launcher ----------------
extern "C" void kernel_launch(void* const* d_in, const int* in_sizes, int n_in,
                              void* d_out, int out_size, void* d_ws, size_t ws_size,
                              hipStream_t stream) {
  const float* x    = (const float*)d_in[0];
  const int*   eidx = (const int*)  d_in[1];
  const int*   batch= (const int*)  d_in[2];
  const float* W1   = (const float*)d_in[3];
  const float* as1w = (const float*)d_in[4];
  const float* ad1w = (const float*)d_in[5];
  const float* b1   = (const float*)d_in[6];
  const float* W2   = (const float*)d_in[7];
  const float* as2w = (const float*)d_in[8];
  const float* ad2w = (const float*)d_in[9];
  const float* b2   = (const float*)d_in[10];
  float* out = (float*)d_out;

  int N = in_sizes[0] / 128;
  int E = in_sizes[1] / 2;
  int G = out_size / 16;
  const int* esrc = eidx;
  const int* edst = eidx + E;

  int NB = (N + 127) >> 7;
  int nblkA = (E + EPB - 1) / EPB;

  char* p = (char*)d_ws;
  auto alloc = [&](size_t bytes) {
    char* r = p;
    p += (bytes + 255) & ~(size_t)255;
    return r;
  };
  ushort_t* h1b = (ushort_t*)alloc((size_t)N * 128 * 2);
  ushort_t* hmidb = (ushort_t*)alloc((size_t)N * 128 * 2);
  ushort_t* h2b = (ushort_t*)alloc((size_t)N * 16 * 2);
  float* as1  = (float*)alloc((size_t)N * 8 * 4);
  float* ad1  = (float*)alloc((size_t)N * 8 * 4);
  float* as2  = (float*)alloc((size_t)N * 4);
  float* ad2  = (float*)alloc((size_t)N * 4);
  // union: pairs (E*4 B) is dead before alpha1/alpha2 are produced
  size_t a1sz = (size_t)E * 8 * 2, a2sz = (size_t)E * 4;
  size_t unionSz = a1sz + a2sz;
  char* U = alloc(unionSz);
  uint_t* pairs = (uint_t*)U;
  ushort_t* alpha1 = (ushort_t*)U;
  float* alpha2 = (float*)(U + a1sz);
  float* pooled = (float*)alloc((size_t)(G * 16 + G) * 4);
  float* cntb = pooled + G * 16;
  int* rowptr = (int*)alloc((size_t)(N + 1) * 4);
  int* csr    = (int*)alloc((size_t)E * 4);
  int* gcount = (int*)alloc((size_t)(NBMAX + 1) * 4);
  int* boff   = (int*)alloc((size_t)(NBMAX + 1) * 4);
  int* myBase = (int*)alloc((size_t)nblkA * NB * 4);

  hipMemsetAsync(gcount, 0, (size_t)(NBMAX + 1) * 4, stream);
  hipMemsetAsync(pooled, 0, (size_t)(G * 16 + G) * 4, stream);

  bucket_hist_kernel<<<nblkA, 256, 0, stream>>>(edst, gcount, myBase, E, NB);
  bucket_scan_kernel<<<1, 1024, 0, stream>>>(gcount, boff, NB);
  bucket_scatter_kernel<<<nblkA, 256, 0, stream>>>(esrc, edst, boff, myBase, pairs, E, NB);
  bucket_csr_kernel<<<NB, 128, 0, stream>>>(pairs, boff, rowptr, csr, N, NB);

  gemm1_att1_kernel<<<(N + 127) / 128, 256, 0, stream>>>(x, W1, as1w, ad1w, h1b, as1, ad1, N);
  alpha1_kernel<<<(N + 3) / 4, 256, 0, stream>>>(rowptr, csr, as1, ad1, alpha1, N);
  gat1_agg_kernel<<<(N + 3) / 4, 256, 0, stream>>>(rowptr, csr, h1b, alpha1, b1, hmidb, N);
  gemm2_att2_kernel<<<(N + 63) / 64, 256, 0, stream>>>(hmidb, W2, as2w, ad2w, h2b, as2, ad2, N);
  alpha2_kernel<<<(N + 3) / 4, 256, 0, stream>>>(rowptr, csr, as2, ad2, alpha2, N);
  gat2_agg_kernel<<<(N + 15) / 16, 256, 0, stream>>>(rowptr, csr, h2b, alpha2, b2, batch, pooled, cntb, N, G);
  final_kernel<<<1, (G + 63) / 64 * 64, 0, stream>>>(pooled, cntb, out, G);
}

// Round 11
// 383.021 us; speedup vs baseline: 1.1147x; 1.0555x over previous
//
#include <hip/hip_runtime.h>
#include <cstdint>
#include <cstddef>

typedef unsigned short ushort_t;
typedef unsigned int uint_t;
typedef __attribute__((ext_vector_type(8))) short bf16x8;
typedef __attribute__((ext_vector_type(4))) float f32x4;

#define NBMAX 1024   // max buckets (N <= 131072)
#define EPB   4096   // edges per block in hist/scatter passes (391 blocks at E=1.6M)
#define LDK   136    // padded k-stride (bf16 units) for LDS W^T

__device__ inline ushort_t f2bf(float f) {
  uint_t u = __float_as_uint(f);
  uint_t r = (u + 0x7fffu + ((u >> 16) & 1u)) >> 16;
  return (ushort_t)r;
}
__device__ inline float bfl(uint_t u) { return __uint_as_float(u << 16); }
__device__ inline float bfh(uint_t u) { return __uint_as_float(u & 0xffff0000u); }
__device__ inline float bf1(ushort_t v) { return __uint_as_float(((uint_t)v) << 16); }

// ---------------- CSR construction: bucketed counting sort ----------------

__global__ void bucket_hist_kernel(const int* __restrict__ edst, int* __restrict__ gcount,
                                   int* __restrict__ myBase, int E, int NB) {
  __shared__ int hist[NBMAX];
  int t = threadIdx.x;
  int blk = blockIdx.x;
  for (int i = t; i < NB; i += 256) hist[i] = 0;
  __syncthreads();
  int b0 = blk * EPB, e1 = min(b0 + EPB, E);
  for (int i = b0 + t; i < e1; i += 256) atomicAdd(&hist[edst[i] >> 7], 1);
  __syncthreads();
  for (int i = t; i < NB; i += 256) {
    int c = hist[i];
    myBase[(size_t)blk * NB + i] = c ? atomicAdd(&gcount[i], c) : 0;
  }
}

// scan of bucket counts -> boff[NB+1]; also zeroes pooled/cntb (used much later).
__global__ void bucket_scan_kernel(const int* __restrict__ gcount, int* __restrict__ boff, int NB,
                                   float* __restrict__ pooled, int poolsz) {
  __shared__ int ws[16];
  int t = threadIdx.x;
  for (int i = t; i < poolsz; i += 1024) pooled[i] = 0.f;
  int lane = t & 63, w = t >> 6;
  int v = (t < NB) ? gcount[t] : 0;
  for (int o = 1; o < 64; o <<= 1) { int y = __shfl_up(v, o); if (lane >= o) v += y; }
  if (lane == 63) ws[w] = v;
  __syncthreads();
  if (t < 16) {
    int s = ws[t];
    for (int o = 1; o < 16; o <<= 1) { int y = __shfl_up(s, o); if (t >= o) s += y; }
    ws[t] = s;
  }
  __syncthreads();
  if (w > 0) v += ws[w - 1];
  if (t < NB) boff[t + 1] = v;
  if (t == 0) boff[0] = 0;
}

// packed pair: (dst & 127) << 25 | src   (requires src < 2^25)
__global__ void bucket_scatter_kernel(const int* __restrict__ esrc, const int* __restrict__ edst,
                                      const int* __restrict__ boff, const int* __restrict__ myBase,
                                      uint_t* __restrict__ pairs, int E, int NB) {
  __shared__ int cursor[NBMAX];
  int t = threadIdx.x;
  int blk = blockIdx.x;
  for (int i = t; i < NB; i += 256) cursor[i] = boff[i] + myBase[(size_t)blk * NB + i];
  __syncthreads();
  int b0 = blk * EPB, e1 = min(b0 + EPB, E);
  for (int i = b0 + t; i < e1; i += 256) {
    int d = edst[i], s = esrc[i];
    int pos = atomicAdd(&cursor[d >> 7], 1);
    pairs[pos] = ((uint_t)(d & 127) << 25) | (uint_t)s;
  }
}

__global__ void bucket_csr_kernel(const uint_t* __restrict__ pairs, const int* __restrict__ boff,
                                  int* __restrict__ rowptr, int* __restrict__ csr, int n, int NB) {
  __shared__ int cnt[128];
  __shared__ int ws2[2];
  int b = blockIdx.x;
  int t = threadIdx.x;   // 128 threads
  int lo = boff[b], hi = boff[b + 1];
  int D0 = b << 7;
  cnt[t] = 0;
  __syncthreads();
  for (int i = lo + t; i < hi; i += 128) atomicAdd(&cnt[pairs[i] >> 25], 1);
  __syncthreads();
  int lane = t & 63, w = t >> 6;
  int v = cnt[t];
  int vx = v;
  for (int o = 1; o < 64; o <<= 1) { int y = __shfl_up(vx, o); if (lane >= o) vx += y; }
  if (lane == 63) ws2[w] = vx;
  __syncthreads();
  int incl = vx + (w ? ws2[0] : 0);
  int excl = incl - v;
  int d = D0 + t;
  if (d <= n) rowptr[d] = lo + excl;
  __syncthreads();
  cnt[t] = excl;
  __syncthreads();
  for (int i = lo + t; i < hi; i += 128) {
    uint_t pr = pairs[i];
    int pos = atomicAdd(&cnt[pr >> 25], 1);
    csr[lo + pos] = (int)(pr & 0x1FFFFFFu);
  }
}

// ---------------- GEMM1 + att1 fused (MFMA): h1b(bf16) = x@W1; a_s/a_d (f32) ----------------
__global__ void gemm1_att1_kernel(const float* __restrict__ x, const float* __restrict__ W,
                                  const float* __restrict__ asw, const float* __restrict__ adw,
                                  ushort_t* __restrict__ h1b, float* __restrict__ a_s,
                                  float* __restrict__ a_d, int n) {
  __shared__ ushort_t wT[128 * LDK];
  int t = threadIdx.x;
  {
    int nn = t & 127;
    int kp0 = t >> 7;                    // 0..1
    for (int kp = kp0; kp < 64; kp += 2) {
      float w0 = W[(size_t)(2 * kp) * 128 + nn];
      float w1 = W[(size_t)(2 * kp + 1) * 128 + nn];
      *(uint_t*)&wT[nn * LDK + 2 * kp] = (uint_t)f2bf(w0) | ((uint_t)f2bf(w1) << 16);
    }
  }
  __syncthreads();

  int lane = t & 63, w = t >> 6;
  int g = lane >> 4, cl = lane & 15;

  #pragma unroll
  for (int rt = 0; rt < 2; ++rt) {
    int rowA = blockIdx.x * 128 + rt * 64 + w * 16 + cl;
    const float* xr = x + (size_t)(rowA < n ? rowA : 0) * 128;

    bf16x8 afr[4];
    #pragma unroll
    for (int c = 0; c < 4; ++c) {
      float4 v0 = *(const float4*)(xr + c * 32 + g * 8);
      float4 v1 = *(const float4*)(xr + c * 32 + g * 8 + 4);
      bf16x8 a;
      a[0] = (short)f2bf(v0.x); a[1] = (short)f2bf(v0.y);
      a[2] = (short)f2bf(v0.z); a[3] = (short)f2bf(v0.w);
      a[4] = (short)f2bf(v1.x); a[5] = (short)f2bf(v1.y);
      a[6] = (short)f2bf(v1.z); a[7] = (short)f2bf(v1.w);
      afr[c] = a;
    }

    int orow0 = blockIdx.x * 128 + rt * 64 + w * 16 + g * 4;
    #pragma unroll 2
    for (int tt = 0; tt < 8; ++tt) {
      f32x4 acc = {0.f, 0.f, 0.f, 0.f};
      #pragma unroll
      for (int c = 0; c < 4; ++c) {
        bf16x8 bfr = *(const bf16x8*)&wT[(tt * 16 + cl) * LDK + c * 32 + g * 8];
        acc = __builtin_amdgcn_mfma_f32_16x16x32_bf16(afr[c], bfr, acc, 0, 0, 0);
      }
      float asv = asw[tt * 16 + cl], adv = adw[tt * 16 + cl];
      float ps[4], pd[4];
      ushort_t hb[4];
      #pragma unroll
      for (int r = 0; r < 4; ++r) {
        float v = acc[r];
        hb[r] = f2bf(v);
        ps[r] = v * asv; pd[r] = v * adv;
      }
      #pragma unroll
      for (int o = 1; o < 16; o <<= 1) {
        #pragma unroll
        for (int r = 0; r < 4; ++r) { ps[r] += __shfl_xor(ps[r], o); pd[r] += __shfl_xor(pd[r], o); }
      }
      #pragma unroll
      for (int r = 0; r < 4; ++r) {
        int rr = orow0 + r;
        if (rr < n) {
          h1b[(size_t)rr * 128 + tt * 16 + cl] = hb[r];
          if (cl == 0) {
            a_s[(size_t)rr * 8 + tt] = ps[r];
            a_d[(size_t)rr * 8 + tt] = pd[r];
          }
        }
      }
    }
  }
}

// ---------------- GAT layer 1 FUSED: softmax (phase A) + weighted gather (phase B) ----------------
// One wave per dst. Phase A: lane=(el=t>>3, h=t&7), e -> LDS, 3-butterfly online softmax.
// Phase B: lane=(slot=t>>4, c8=t&15), alpha from LDS, 4 edges concurrently.
__global__ void gat1_fused_kernel(const int* __restrict__ rowptr, const int* __restrict__ csr_src,
                                  const ushort_t* __restrict__ h1b,
                                  const float* __restrict__ a_s, const float* __restrict__ a_d,
                                  const float* __restrict__ b1, ushort_t* __restrict__ hmidb, int n) {
  __shared__ float e_lds[4][64][8];
  int t = threadIdx.x & 63;
  int w = threadIdx.x >> 6;
  int dst = blockIdx.x * 4 + w;
  if (dst >= n) return;
  int beg = rowptr[dst], end = rowptr[dst + 1];
  int deg = end - beg;

  int h = t & 7, el = t >> 3;
  float adv = a_d[(size_t)dst * 8 + h];
  float M = -1e30f, S = 0.f;

  int slot = t >> 4, c8 = t & 15;
  int hh = c8 >> 1;
  float acc[8] = {};

  if (deg > 0 && deg <= 64) {
    // ---- phase A (fast): e cached in wave-private LDS ----
    int nch = (deg + 7) >> 3;
    for (int it = 0; it < nch; ++it) {
      int eidx = beg + it * 8 + el;
      bool valid = eidx < end;
      int s = csr_src[valid ? eidx : beg];
      float eraw = a_s[(size_t)s * 8 + h] + adv;
      eraw = eraw > 0.f ? eraw : 0.2f * eraw;
      e_lds[w][it * 8 + el][h] = eraw;
      float e = valid ? eraw : -1e30f;
      float m = e;
      m = fmaxf(m, __shfl_xor(m, 8));
      m = fmaxf(m, __shfl_xor(m, 16));
      m = fmaxf(m, __shfl_xor(m, 32));
      float nm = fmaxf(M, m);
      float p = valid ? __expf(e - nm) : 0.f;
      float ps = p;
      ps += __shfl_xor(ps, 8);
      ps += __shfl_xor(ps, 16);
      ps += __shfl_xor(ps, 32);
      S = S * __expf(M - nm) + ps;
      M = nm;
    }
    float inv = 1.f / (S + 1e-16f);
    for (int it = 0; it < nch; ++it) {
      int pos = it * 8 + el;
      if (beg + pos < end)
        e_lds[w][pos][h] = __expf(e_lds[w][pos][h] - M) * inv;
    }
    // ---- phase B: alpha from LDS, 4 edges/wave ----
    for (int i = slot; i < deg; i += 4) {
      int si = csr_src[beg + i];
      float a = e_lds[w][i][hh];
      uint4 hv = *(const uint4*)(h1b + (size_t)si * 128 + c8 * 8);
      acc[0] = fmaf(a, bfl(hv.x), acc[0]);
      acc[1] = fmaf(a, bfh(hv.x), acc[1]);
      acc[2] = fmaf(a, bfl(hv.y), acc[2]);
      acc[3] = fmaf(a, bfh(hv.y), acc[3]);
      acc[4] = fmaf(a, bfl(hv.z), acc[4]);
      acc[5] = fmaf(a, bfh(hv.z), acc[5]);
      acc[6] = fmaf(a, bfl(hv.w), acc[6]);
      acc[7] = fmaf(a, bfh(hv.w), acc[7]);
    }
  } else if (deg > 64) {
    // ---- phase A (slow): streaming, no LDS cache ----
    for (int base = beg; base < end; base += 8) {
      int eidx = base + el;
      bool valid = eidx < end;
      int s = csr_src[valid ? eidx : beg];
      float e = a_s[(size_t)s * 8 + h] + adv;
      e = e > 0.f ? e : 0.2f * e;
      e = valid ? e : -1e30f;
      float m = e;
      m = fmaxf(m, __shfl_xor(m, 8));
      m = fmaxf(m, __shfl_xor(m, 16));
      m = fmaxf(m, __shfl_xor(m, 32));
      float nm = fmaxf(M, m);
      float p = valid ? __expf(e - nm) : 0.f;
      float ps = p;
      ps += __shfl_xor(ps, 8);
      ps += __shfl_xor(ps, 16);
      ps += __shfl_xor(ps, 32);
      S = S * __expf(M - nm) + ps;
      M = nm;
    }
    float inv = 1.f / (S + 1e-16f);
    // broadcast this lane's needed head stats from lane hh (whose h == hh)
    float Mh = __shfl(M, hh);
    float invh = __shfl(inv, hh);
    float advh = __shfl(adv, hh);
    for (int i = slot; i < deg; i += 4) {
      int si = csr_src[beg + i];
      float eraw = a_s[(size_t)si * 8 + hh] + advh;
      eraw = eraw > 0.f ? eraw : 0.2f * eraw;
      float a = __expf(eraw - Mh) * invh;
      uint4 hv = *(const uint4*)(h1b + (size_t)si * 128 + c8 * 8);
      acc[0] = fmaf(a, bfl(hv.x), acc[0]);
      acc[1] = fmaf(a, bfh(hv.x), acc[1]);
      acc[2] = fmaf(a, bfl(hv.y), acc[2]);
      acc[3] = fmaf(a, bfh(hv.y), acc[3]);
      acc[4] = fmaf(a, bfl(hv.z), acc[4]);
      acc[5] = fmaf(a, bfh(hv.z), acc[5]);
      acc[6] = fmaf(a, bfl(hv.w), acc[6]);
      acc[7] = fmaf(a, bfh(hv.w), acc[7]);
    }
  }

  #pragma unroll
  for (int i = 0; i < 8; ++i) {
    acc[i] += __shfl_xor(acc[i], 16);
    acc[i] += __shfl_xor(acc[i], 32);
  }
  if (slot == 0) {
    ushort_t ob[8];
    #pragma unroll
    for (int i = 0; i < 8; ++i) {
      float v = acc[i] + b1[c8 * 8 + i];
      v = v > 0.f ? v : (__expf(v) - 1.f);
      ob[i] = f2bf(v);
    }
    *(uint4*)(hmidb + (size_t)dst * 128 + c8 * 8) = *(uint4*)ob;
  }
}

// ---------------- GEMM2 + att2 fused (MFMA): h2b = hmid(bf16) @ W2; a_s2/a_d2 ----------------
__global__ void gemm2_att2_kernel(const ushort_t* __restrict__ hmidb, const float* __restrict__ W2,
                                  const float* __restrict__ asw, const float* __restrict__ adw,
                                  ushort_t* __restrict__ h2b, float* __restrict__ a_s2,
                                  float* __restrict__ a_d2, int n) {
  __shared__ ushort_t wT[16 * LDK];
  int t = threadIdx.x;
  if (t < 128) {
    int nn = t & 15, kp0 = t >> 4;     // 0..7
    for (int kp = kp0; kp < 64; kp += 8) {
      float w0 = W2[(size_t)(2 * kp) * 16 + nn];
      float w1 = W2[(size_t)(2 * kp + 1) * 16 + nn];
      *(uint_t*)&wT[nn * LDK + 2 * kp] = (uint_t)f2bf(w0) | ((uint_t)f2bf(w1) << 16);
    }
  }
  __syncthreads();

  int lane = t & 63, w = t >> 6;
  int g = lane >> 4, cl = lane & 15;
  int rowA = blockIdx.x * 64 + w * 16 + cl;
  const ushort_t* hr = hmidb + (size_t)(rowA < n ? rowA : 0) * 128;

  f32x4 acc = {0.f, 0.f, 0.f, 0.f};
  #pragma unroll
  for (int c = 0; c < 4; ++c) {
    bf16x8 afr = *(const bf16x8*)(hr + c * 32 + g * 8);
    bf16x8 bfr = *(const bf16x8*)&wT[cl * LDK + c * 32 + g * 8];
    acc = __builtin_amdgcn_mfma_f32_16x16x32_bf16(afr, bfr, acc, 0, 0, 0);
  }
  float asv = asw[cl], adv = adw[cl];
  float ps[4], pd[4];
  ushort_t hb[4];
  #pragma unroll
  for (int r = 0; r < 4; ++r) {
    float v = acc[r];
    hb[r] = f2bf(v);
    ps[r] = v * asv; pd[r] = v * adv;
  }
  #pragma unroll
  for (int o = 1; o < 16; o <<= 1) {
    #pragma unroll
    for (int r = 0; r < 4; ++r) { ps[r] += __shfl_xor(ps[r], o); pd[r] += __shfl_xor(pd[r], o); }
  }
  int orow0 = blockIdx.x * 64 + w * 16 + g * 4;
  #pragma unroll
  for (int r = 0; r < 4; ++r) {
    int rr = orow0 + r;
    if (rr < n) {
      h2b[(size_t)rr * 16 + cl] = hb[r];
      if (cl == 0) { a_s2[rr] = ps[r]; a_d2[rr] = pd[r]; }
    }
  }
}

// ---------------- alpha2: normalized attention weights, layer 2 (1 head) ----------------
__global__ void alpha2_kernel(const int* __restrict__ rowptr, const int* __restrict__ csr_src,
                              const float* __restrict__ a_s2, const float* __restrict__ a_d2,
                              float* __restrict__ alpha2, int n) {
  int t = threadIdx.x & 63;
  int w = threadIdx.x >> 6;
  int dst = blockIdx.x * 4 + w;
  if (dst >= n) return;
  int beg = rowptr[dst], end = rowptr[dst + 1];
  int deg = end - beg;
  if (deg == 0) return;
  float adv = a_d2[dst];

  if (deg <= 64) {
    int eidx = beg + t;
    bool valid = eidx < end;
    int s = csr_src[valid ? eidx : beg];
    float e = a_s2[s] + adv;
    e = e > 0.f ? e : 0.2f * e;
    float ev = valid ? e : -1e30f;
    float m = ev;
    #pragma unroll
    for (int o = 1; o < 64; o <<= 1) m = fmaxf(m, __shfl_xor(m, o));
    float p = valid ? __expf(ev - m) : 0.f;
    float S = p;
    #pragma unroll
    for (int o = 1; o < 64; o <<= 1) S += __shfl_xor(S, o);
    if (valid) alpha2[eidx] = p / (S + 1e-16f);
    return;
  }

  float M = -1e30f, S = 0.f;
  for (int base = beg; base < end; base += 64) {
    int eidx = base + t;
    bool valid = eidx < end;
    int s = csr_src[valid ? eidx : beg];
    float e = a_s2[s] + adv;
    e = e > 0.f ? e : 0.2f * e;
    e = valid ? e : -1e30f;
    float m = e;
    #pragma unroll
    for (int o = 1; o < 64; o <<= 1) m = fmaxf(m, __shfl_xor(m, o));
    float nm = fmaxf(M, m);
    float p = valid ? __expf(e - nm) : 0.f;
    float ps = p;
    #pragma unroll
    for (int o = 1; o < 64; o <<= 1) ps += __shfl_xor(ps, o);
    S = S * __expf(M - nm) + ps;
    M = nm;
  }
  float inv = 1.f / (S + 1e-16f);
  for (int base = beg; base < end; base += 64) {
    int eidx = base + t;
    if (eidx < end) {
      int s = csr_src[eidx];
      float e = a_s2[s] + adv;
      e = e > 0.f ? e : 0.2f * e;
      alpha2[eidx] = __expf(e - M) * inv;
    }
  }
}

// ---------------- GAT layer 2 aggregate + pooled atomics (16-lane group per dst) ----------------
__global__ void gat2_agg_kernel(const int* __restrict__ rowptr, const int* __restrict__ csr_src,
                                const ushort_t* __restrict__ h2b,
                                const float* __restrict__ alpha2, const float* __restrict__ b2,
                                const int* __restrict__ batch,
                                float* __restrict__ pooled, float* __restrict__ cntb,
                                int n, int G) {
  __shared__ float pooledL[17][16];
  __shared__ float cntL[17];
  __shared__ int   s_lds[16][16];
  __shared__ float a_lds[16][16];
  int t = threadIdx.x;
  if (t < 17) cntL[t] = 0.f;
  for (int i = t; i < 17 * 16; i += 256) ((float*)pooledL)[i] = 0.f;
  __syncthreads();

  int grp = t >> 4, c = t & 15;
  int dst = blockIdx.x * 16 + grp;
  int gfirst = batch[blockIdx.x * 16];

  if (dst < n) {
    int beg = rowptr[dst], end = rowptr[dst + 1];
    float acc = 0.f;
    for (int base = beg; base < end; base += 16) {
      int idx = base + c;
      bool v = idx < end;
      s_lds[grp][c] = v ? csr_src[idx] : 0;
      a_lds[grp][c] = v ? alpha2[idx] : 0.f;
      #pragma unroll
      for (int j = 0; j < 16; ++j) {
        acc = fmaf(a_lds[grp][j], bf1(h2b[(size_t)s_lds[grp][j] * 16 + c]), acc);
      }
    }
    float v = acc + b2[c];
    int g = batch[dst];
    int gi = g - gfirst;
    if (gi <= 16) {
      atomicAdd(&pooledL[gi][c], v);
      if (c == 0) atomicAdd(&cntL[gi], 1.f);
    } else {
      atomicAdd(&pooled[g * 16 + c], v);
      if (c == 0) atomicAdd(&cntb[g], 1.f);
    }
  }
  __syncthreads();

  int w = t >> 5, lane32 = t & 31;
  for (int gi = w; gi < 17; gi += 8) {
    if (cntL[gi] > 0.f) {
      int g = gfirst + gi;
      if (lane32 < 16) atomicAdd(&pooled[g * 16 + lane32], pooledL[gi][lane32]);
      else if (lane32 == 16) atomicAdd(&cntb[g], cntL[gi]);
    }
  }
}

// ---------------- final: mean + log_softmax ----------------
__global__ void final_kernel(const float* __restrict__ pooled, const float* __restrict__ cntb,
                             float* __restrict__ out, int G) {
  int g = threadIdx.x;
  if (g >= G) return;
  float c = fmaxf(cntb[g], 1.f);
  float v[16];
  float m = -1e30f;
  #pragma unroll
  for (int i = 0; i < 16; ++i) { v[i] = pooled[g * 16 + i] / c; m = fmaxf(m, v[i]); }
  float s = 0.f;
  #pragma unroll
  for (int i = 0; i < 16; ++i) s += __expf(v[i] - m);
  float ls = logf(s);
  #pragma unroll
  for (int i = 0; i < 16; ++i) out[g * 16 + i] = v[i] - m - ls;
}

// ---------------- launcher ----------------
extern "C" void kernel_launch(void* const* d_in, const int* in_sizes, int n_in,
                              void* d_out, int out_size, void* d_ws, size_t ws_size,
                              hipStream_t stream) {
  const float* x    = (const float*)d_in[0];
  const int*   eidx = (const int*)  d_in[1];
  const int*   batch= (const int*)  d_in[2];
  const float* W1   = (const float*)d_in[3];
  const float* as1w = (const float*)d_in[4];
  const float* ad1w = (const float*)d_in[5];
  const float* b1   = (const float*)d_in[6];
  const float* W2   = (const float*)d_in[7];
  const float* as2w = (const float*)d_in[8];
  const float* ad2w = (const float*)d_in[9];
  const float* b2   = (const float*)d_in[10];
  float* out = (float*)d_out;

  int N = in_sizes[0] / 128;
  int E = in_sizes[1] / 2;
  int G = out_size / 16;
  const int* esrc = eidx;
  const int* edst = eidx + E;

  int NB = (N + 127) >> 7;
  int nblkA = (E + EPB - 1) / EPB;

  char* p = (char*)d_ws;
  auto alloc = [&](size_t bytes) {
    char* r = p;
    p += (bytes + 255) & ~(size_t)255;
    return r;
  };
  ushort_t* h1b = (ushort_t*)alloc((size_t)N * 128 * 2);
  ushort_t* hmidb = (ushort_t*)alloc((size_t)N * 128 * 2);
  ushort_t* h2b = (ushort_t*)alloc((size_t)N * 16 * 2);
  float* as1  = (float*)alloc((size_t)N * 8 * 4);
  float* ad1  = (float*)alloc((size_t)N * 8 * 4);
  float* as2  = (float*)alloc((size_t)N * 4);
  float* ad2  = (float*)alloc((size_t)N * 4);
  // union: pairs (E*4 B) is dead before alpha2 is produced
  char* U = alloc((size_t)E * 4);
  uint_t* pairs = (uint_t*)U;
  float* alpha2 = (float*)U;
  float* pooled = (float*)alloc((size_t)(G * 16 + G) * 4);
  float* cntb = pooled + G * 16;
  int* rowptr = (int*)alloc((size_t)(N + 1) * 4);
  int* csr    = (int*)alloc((size_t)E * 4);
  int* gcount = (int*)alloc((size_t)(NBMAX + 1) * 4);
  int* boff   = (int*)alloc((size_t)(NBMAX + 1) * 4);
  int* myBase = (int*)alloc((size_t)nblkA * NB * 4);

  hipMemsetAsync(gcount, 0, (size_t)(NBMAX + 1) * 4, stream);

  bucket_hist_kernel<<<nblkA, 256, 0, stream>>>(edst, gcount, myBase, E, NB);
  bucket_scan_kernel<<<1, 1024, 0, stream>>>(gcount, boff, NB, pooled, G * 16 + G);
  bucket_scatter_kernel<<<nblkA, 256, 0, stream>>>(esrc, edst, boff, myBase, pairs, E, NB);
  bucket_csr_kernel<<<NB, 128, 0, stream>>>(pairs, boff, rowptr, csr, N, NB);

  gemm1_att1_kernel<<<(N + 127) / 128, 256, 0, stream>>>(x, W1, as1w, ad1w, h1b, as1, ad1, N);
  gat1_fused_kernel<<<(N + 3) / 4, 256, 0, stream>>>(rowptr, csr, h1b, as1, ad1, b1, hmidb, N);
  gemm2_att2_kernel<<<(N + 63) / 64, 256, 0, stream>>>(hmidb, W2, as2w, ad2w, h2b, as2, ad2, N);
  alpha2_kernel<<<(N + 3) / 4, 256, 0, stream>>>(rowptr, csr, as2, ad2, alpha2, N);
  gat2_agg_kernel<<<(N + 15) / 16, 256, 0, stream>>>(rowptr, csr, h2b, alpha2, b2, batch, pooled, cntb, N, G);
  final_kernel<<<1, (G + 63) / 64 * 64, 0, stream>>>(pooled, cntb, out, G);
}